// Round 9
// baseline (391.361 us; speedup 1.0000x reference)
//
#include <hip/hip_runtime.h>
#include <stdint.h>
#include <stddef.h>

#define Bb 128
#define Nn 512
#define Hh 128
#define ROWS (Bb*Nn)

typedef __bf16 bf16;
typedef __bf16 bf16x2 __attribute__((ext_vector_type(2)));
typedef __bf16 bf16x4 __attribute__((ext_vector_type(4)));
typedef __bf16 bf16x8 __attribute__((ext_vector_type(8)));
typedef float  f32x4  __attribute__((ext_vector_type(4)));

__device__ __forceinline__ void glds16(const void* g, void* l) {
  __builtin_amdgcn_global_load_lds(
      (const __attribute__((address_space(1))) void*)g,
      (__attribute__((address_space(3))) void*)l, 16, 0, 0);
}

// -------------------------------------------------- weight prep (all in one)
// fp32 W[k][c] -> bf16 W^T[c][k ^ ((c&7)<<3)]  (swizzle pre-applied)
__global__ __launch_bounds__(256) void prep_all(
    const float* __restrict__ eW1, const float* __restrict__ Wm,
    const float* __restrict__ Wu, bf16* __restrict__ WTe,
    bf16* __restrict__ WTm, bf16* __restrict__ WTu) {
  int idx = blockIdx.x*256 + threadIdx.x;
  if (idx < 16384) {                       // eW1: 128x128
    int k = idx >> 7, c = idx & 127;
    WTe[c*128 + (k ^ ((c & 7) << 3))] = (bf16)eW1[idx];
  } else if (idx < 16384 + 49152) {        // Wm: 3x128x128
    int sub = idx - 16384;
    int m = sub >> 14, r = sub & 16383;
    int k = r >> 7, c = r & 127;
    WTm[m*16384 + c*128 + (k ^ ((c & 7) << 3))] = (bf16)Wm[sub];
  } else if (idx < 16384 + 49152 + 98304) { // Wu: 3x256x128
    int sub = idx - 65536;
    int m = sub >> 15, r = sub & 32767;
    int k = r >> 7, c = r & 127;
    WTu[m*32768 + c*256 + (k ^ ((c & 7) << 3))] = (bf16)Wu[sub];
  }
}

// -------------------------------------------------- fused embed L1+L2+msg0
// h = relu(relu(jets@W0+b0)@W1+b1); msgT0 = relu(h@Wm0+bm0)^T. 128 rows/block.
__global__ __launch_bounds__(256) void embed_msg0(
    const float* __restrict__ jets, const float* __restrict__ W0,
    const float* __restrict__ b0, const bf16* __restrict__ WTe,
    const float* __restrict__ b1, const bf16* __restrict__ WTm0,
    const float* __restrict__ bm0, bf16* __restrict__ h,
    bf16* __restrict__ msgT) {
  __shared__ float sW0[8*128];
  __shared__ float sb0[128];
  __shared__ bf16 h0s[128*128];   // swizzled; reused for h-tile later
  __shared__ bf16 sWT[128*128];   // swizzled W1^T
  const int t = threadIdx.x;
  const int w = t >> 6, lane = t & 63, l15 = lane & 15, g = lane >> 4;
  const int row_blk = blockIdx.x*128;
  for (int q = w; q < 32; q += 4)
    glds16((const char*)WTe + q*1024 + lane*16, (char*)(void*)sWT + q*1024);
  for (int i = t; i < 8*128; i += 256) sW0[i] = W0[i];
  if (t < 128) sb0[t] = b0[t];
  __syncthreads();
  // layer 1: thread owns 1 row, 64 cols
  {
    const int row = t & 127, colbase = (t >> 7) * 64;
    const float4* jp = (const float4*)(jets + ((size_t)row_blk + row)*8);
    float4 x0 = jp[0], x1 = jp[1];
    float x[8] = {x0.x,x0.y,x0.z,x0.w,x1.x,x1.y,x1.z,x1.w};
    const int sw = (row & 7) << 3;
#pragma unroll
    for (int cg = 0; cg < 16; ++cg) {
      int c0 = colbase + cg*4;
      bf16x4 o;
#pragma unroll
      for (int j = 0; j < 4; ++j) {
        float a = sb0[c0+j];
#pragma unroll
        for (int f = 0; f < 8; ++f) a = fmaf(x[f], sW0[f*128 + c0 + j], a);
        o[j] = (bf16)fmaxf(a, 0.f);
      }
      *(bf16x4*)(h0s + row*128 + (c0 ^ sw)) = o;
    }
  }
  __syncthreads();
  // layer 2: MFMA, 4 waves 2x2
  const int wr = (w & 1)*64, wc = (w >> 1)*64;
  f32x4 acc[4][4];
#pragma unroll
  for (int m = 0; m < 4; ++m)
#pragma unroll
    for (int n = 0; n < 4; ++n) acc[m][n] = (f32x4){0.f,0.f,0.f,0.f};
#pragma unroll
  for (int kk = 0; kk < 128; kk += 32) {
    bf16x8 bfr[4], wfr[4];
#pragma unroll
    for (int n = 0; n < 4; ++n) {
      int row = wr + n*16 + l15;
      bfr[n] = *(const bf16x8*)(h0s + row*128 + ((kk + 8*g) ^ ((row & 7) << 3)));
    }
#pragma unroll
    for (int m = 0; m < 4; ++m) {
      int c = wc + m*16 + l15;
      wfr[m] = *(const bf16x8*)(sWT + c*128 + ((kk + 8*g) ^ ((c & 7) << 3)));
    }
#pragma unroll
    for (int m = 0; m < 4; ++m)
#pragma unroll
      for (int n = 0; n < 4; ++n)
        acc[m][n] = __builtin_amdgcn_mfma_f32_16x16x32_bf16(wfr[m], bfr[n], acc[m][n], 0,0,0);
  }
  __syncthreads();   // everyone done reading h0s before overwrite
#pragma unroll
  for (int m = 0; m < 4; ++m) {
    f32x4 bs = *(const f32x4*)(b1 + wc + m*16 + g*4);
#pragma unroll
    for (int n = 0; n < 4; ++n) {
      int lr = wr + n*16 + l15;
      int r = row_blk + lr;
      int c0 = wc + m*16 + g*4;
      bf16x4 o;
#pragma unroll
      for (int j = 0; j < 4; ++j) o[j] = (bf16)fmaxf(acc[m][n][j] + bs[j], 0.f);
      *(bf16x4*)(h + (size_t)r*128 + c0) = o;
      *(bf16x4*)(h0s + lr*128 + (c0 ^ ((lr & 7) << 3))) = o;
    }
  }
  __syncthreads();
  // msg0: msgT = relu(htile @ Wm0 + bm0), TRANSOUT; Wm0 frags from global(L2)
  {
    f32x4 acc2[4][4];
#pragma unroll
    for (int m = 0; m < 4; ++m)
#pragma unroll
      for (int n = 0; n < 4; ++n) acc2[m][n] = (f32x4){0.f,0.f,0.f,0.f};
#pragma unroll
    for (int kk = 0; kk < 128; kk += 32) {
      bf16x8 bfr[4], wfr[4];
#pragma unroll
      for (int n = 0; n < 4; ++n) {
        int lr = wr + n*16 + l15;
        bfr[n] = *(const bf16x8*)(h0s + lr*128 + ((kk + 8*g) ^ ((lr & 7) << 3)));
      }
#pragma unroll
      for (int m = 0; m < 4; ++m) {
        int c = wc + m*16 + l15;
        wfr[m] = *(const bf16x8*)(WTm0 + c*128 + ((kk + 8*g) ^ ((c & 7) << 3)));
      }
#pragma unroll
      for (int m = 0; m < 4; ++m)
#pragma unroll
        for (int n = 0; n < 4; ++n)
          acc2[m][n] = __builtin_amdgcn_mfma_f32_16x16x32_bf16(bfr[n], wfr[m], acc2[m][n], 0,0,0);
    }
    const int b = row_blk >> 9;
    const int rbase = (row_blk & 511) + wr;
#pragma unroll
    for (int m = 0; m < 4; ++m) {
      int c = wc + m*16 + l15;
      float bc = bm0[c];
#pragma unroll
      for (int n = 0; n < 4; ++n) {
        int rl = rbase + n*16 + g*4;
        bf16x4 o;
#pragma unroll
        for (int j = 0; j < 4; ++j) o[j] = (bf16)fmaxf(acc2[m][n][j] + bc, 0.f);
        *(bf16x4*)(msgT + ((size_t)(b*128 + c))*512 + rl) = o;
      }
    }
  }
}

// -------------------------------------------------- persistent 3-iteration MP
// Round-7 geometry (wave=32 rows in A, 64x64 in B/C, 128-row blocks), but all
// 3 iterations in one kernel with per-batch flags: block (b,ic) of iter t
// waits only for the 4 producers (b,*) of iter t-1 -> batches pipeline.
// LDS 52KB (htile overlays aggs; Xs/cbs persistent, staged ONCE).
// Co-residency: 512 blocks x 52KB -> 3 blocks/CU capacity >= 2 needed;
// __launch_bounds__(256,2) caps VGPR so all 512 are resident (no deadlock).
__global__ __launch_bounds__(256, 2) void mp_persist(
    const float* __restrict__ jets, const float* __restrict__ mask,
    bf16* __restrict__ msgA, bf16* __restrict__ msgB,
    bf16* __restrict__ h,
    const bf16* __restrict__ WTu_all, const float* __restrict__ bu_all,
    const bf16* __restrict__ WTm_all, const float* __restrict__ bm_all,
    int* __restrict__ flags) {
  __shared__ __align__(16) char smem[53248];
  float* Xs   = (float*)smem;                 // [512*9] 18KB, persistent
  float* cbs  = (float*)(smem + 18432);       // [512]    2KB, persistent
  bf16*  work = (bf16*)(smem + 20480);        // [128][128] 32KB: aggs then htile
  const int t = threadIdx.x;
  const int b  = blockIdx.x & 127;            // XCD-pinned batch
  const int ic = blockIdx.x >> 7;             // 0..3
  const int i0 = ic*128;
  const int w = t >> 6, lane = t & 63, l15 = lane & 15, g = lane >> 4;
  const int wr = (w & 1)*64, wc = (w >> 1)*64;

  // ---- stage Xs / cbs once for all 3 iterations
  const float* jb = jets + (size_t)b*Nn*8;
  for (int j = t; j < Nn; j += 256) {
    float s2 = 0.f;
#pragma unroll
    for (int f = 0; f < 8; ++f) { float v = jb[j*8+f]; Xs[j*9+f] = v; s2 = fmaf(v,v,s2); }
    cbs[j] = s2 + (mask[(size_t)b*Nn+j] > 0.f ? 0.f : 1e9f);
  }
  __syncthreads();

  const int i0w = i0 + w*32;        // wave's 32 A-rows
  float r_i[2];                     // 1/l_i, computed at it==0, reused after

  for (int it = 0; it < 3; ++it) {
    if (it > 0) {
      if (t == 0) {
        while (__hip_atomic_load(flags + (it-1)*128 + b, __ATOMIC_RELAXED,
                                 __HIP_MEMORY_SCOPE_AGENT) < 4)
          __builtin_amdgcn_s_sleep(2);
        (void)__hip_atomic_load(flags + (it-1)*128 + b, __ATOMIC_ACQUIRE,
                                __HIP_MEMORY_SCOPE_AGENT);
      }
      __syncthreads();   // also protects work region (prev C reads done)
    }
    const bf16* msrc = (it & 1) ? msgB : msgA;
    bf16*       mdst = (it & 1) ? msgA : msgB;
    const bf16*  WTu = WTu_all + (size_t)it*256*128;
    const float*  bu = bu_all + it*128;

    // ================= Phase A: agg -> work (swizzled aggs tile)
    {
      float xi2[2][8], sqi[2], lsum[2];
#pragma unroll
      for (int r = 0; r < 2; ++r) {
        int i = i0w + r*16 + l15;
        float sq = 0.f;
#pragma unroll
        for (int f = 0; f < 8; ++f) {
          float v = Xs[i*9+f];
          xi2[r][f] = 2.f*v;
          sq = fmaf(v, v, sq);
        }
        sqi[r] = sq;
        lsum[r] = 0.f;
      }
      f32x4 acc[2][8];
#pragma unroll
      for (int r = 0; r < 2; ++r)
#pragma unroll
        for (int m = 0; m < 8; ++m) acc[r][m] = (f32x4){0.f,0.f,0.f,0.f};
      const bf16* mB = msrc + (size_t)b*128*512;
#pragma unroll 2
      for (int j0 = 0; j0 < Nn; j0 += 32) {
        bf16x8 afr[8];
#pragma unroll
        for (int m = 0; m < 8; ++m)
          afr[m] = *(const bf16x8*)(mB + (size_t)(m*16 + l15)*512 + j0 + 8*g);
        bf16x8 pfr[2];
#pragma unroll
        for (int r = 0; r < 2; ++r)
#pragma unroll
          for (int e = 0; e < 8; ++e) {
            int j = j0 + 8*g + e;
            float d = -(cbs[j] + sqi[r]);
#pragma unroll
            for (int f = 0; f < 8; ++f) d = fmaf(xi2[r][f], Xs[j*9+f], d);
            float ev = __expf(d);
            if (it == 0) lsum[r] += ev;
            pfr[r][e] = (bf16)ev;
          }
#pragma unroll
        for (int m = 0; m < 8; ++m)
#pragma unroll
          for (int r = 0; r < 2; ++r)
            acc[r][m] = __builtin_amdgcn_mfma_f32_16x16x32_bf16(afr[m], pfr[r], acc[r][m], 0,0,0);
      }
      if (it == 0) {
#pragma unroll
        for (int r = 0; r < 2; ++r) {
          float s = lsum[r];
          s += __shfl_xor(s, 16, 64);
          s += __shfl_xor(s, 32, 64);
          r_i[r] = 1.f/s;
        }
      }
#pragma unroll
      for (int r = 0; r < 2; ++r) {
        int lr = w*32 + r*16 + l15;
#pragma unroll
        for (int m = 0; m < 8; ++m) {
          bf16x4 o;
#pragma unroll
          for (int j = 0; j < 4; ++j) o[j] = (bf16)(acc[r][m][j] * r_i[r]);
          int c0 = m*16 + g*4;
          *(bf16x4*)(work + lr*128 + (c0 ^ ((lr & 7) << 3))) = o;
        }
      }
    }
    __syncthreads();   // aggs visible to all waves

    // ================= Phase B: h_new = relu([h|agg] @ Wu + bu) * mask
    const size_t growbase = (size_t)b*Nn + i0;
    {
      f32x4 acc[4][4];
#pragma unroll
      for (int m = 0; m < 4; ++m)
#pragma unroll
        for (int n = 0; n < 4; ++n) acc[m][n] = (f32x4){0.f,0.f,0.f,0.f};
#pragma unroll
      for (int kk = 0; kk < 256; kk += 32) {
        bf16x8 bfr[4];
        if (kk < 128) {
#pragma unroll
          for (int n = 0; n < 4; ++n)
            bfr[n] = *(const bf16x8*)(h + (growbase + wr + n*16 + l15)*128 + kk + 8*g);
        } else {
#pragma unroll
          for (int n = 0; n < 4; ++n) {
            int lr = wr + n*16 + l15;
            int kl = (kk - 128) + 8*g;
            bfr[n] = *(const bf16x8*)(work + lr*128 + (kl ^ ((lr & 7) << 3)));
          }
        }
        bf16x8 wfr[4];
#pragma unroll
        for (int m = 0; m < 4; ++m) {
          int c = wc + m*16 + l15;
          wfr[m] = *(const bf16x8*)(WTu + c*256 + ((kk + 8*g) ^ ((c & 7) << 3)));
        }
#pragma unroll
        for (int m = 0; m < 4; ++m)
#pragma unroll
          for (int n = 0; n < 4; ++n)
            acc[m][n] = __builtin_amdgcn_mfma_f32_16x16x32_bf16(wfr[m], bfr[n], acc[m][n], 0,0,0);
      }
      __syncthreads();  // h reads + aggs reads drained (before in-place h and htile overlay)
#pragma unroll
      for (int m = 0; m < 4; ++m) {
        f32x4 bs = *(const f32x4*)(bu + wc + m*16 + g*4);
#pragma unroll
        for (int n = 0; n < 4; ++n) {
          int lr = wr + n*16 + l15;
          size_t r = growbase + lr;
          float mv = mask[r];
          bf16x4 o;
#pragma unroll
          for (int j = 0; j < 4; ++j)
            o[j] = (bf16)(fmaxf(acc[m][n][j] + bs[j], 0.f) * mv);
          int c0 = wc + m*16 + g*4;
          *(bf16x4*)(h + r*128 + c0) = o;
          if (it < 2)
            *(bf16x4*)(work + lr*128 + (c0 ^ ((lr & 7) << 3))) = o;  // htile
        }
      }
    }
    if (it >= 2) break;   // last iteration: no next msg
    __syncthreads();      // htile visible

    // ================= Phase C: msg_{it+1} = relu(h_new @ Wm + bm)^T
    {
      const bf16* WTm = WTm_all + (size_t)(it+1)*128*128;
      const float* bm = bm_all + (it+1)*128;
      f32x4 acc[4][4];
#pragma unroll
      for (int m = 0; m < 4; ++m)
#pragma unroll
        for (int n = 0; n < 4; ++n) acc[m][n] = (f32x4){0.f,0.f,0.f,0.f};
#pragma unroll
      for (int kk = 0; kk < 128; kk += 32) {
        bf16x8 bfr[4], wfr[4];
#pragma unroll
        for (int n = 0; n < 4; ++n) {
          int lr = wr + n*16 + l15;
          bfr[n] = *(const bf16x8*)(work + lr*128 + ((kk + 8*g) ^ ((lr & 7) << 3)));
        }
#pragma unroll
        for (int m = 0; m < 4; ++m) {
          int c = wc + m*16 + l15;
          wfr[m] = *(const bf16x8*)(WTm + c*128 + ((kk + 8*g) ^ ((c & 7) << 3)));
        }
#pragma unroll
        for (int m = 0; m < 4; ++m)
#pragma unroll
          for (int n = 0; n < 4; ++n)
            acc[m][n] = __builtin_amdgcn_mfma_f32_16x16x32_bf16(bfr[n], wfr[m], acc[m][n], 0,0,0);
      }
#pragma unroll
      for (int m = 0; m < 4; ++m) {
        int c = wc + m*16 + l15;
        float bc = bm[c];
#pragma unroll
        for (int n = 0; n < 4; ++n) {
          int rl = i0 + wr + n*16 + g*4;
          bf16x4 o;
#pragma unroll
          for (int j = 0; j < 4; ++j) o[j] = (bf16)fmaxf(acc[m][n][j] + bc, 0.f);
          *(bf16x4*)(mdst + ((size_t)(b*128 + c))*512 + rl) = o;
        }
      }
    }
    __threadfence();      // msg stores device-visible
    __syncthreads();      // all waves' stores drained
    if (t == 0)
      __hip_atomic_fetch_add(flags + it*128 + b, 1, __ATOMIC_RELEASE,
                             __HIP_MEMORY_SCOPE_AGENT);
  }
}

// -------------------------------------------------- fused pool + readout
__global__ __launch_bounds__(256) void pool_readout(
    const bf16* __restrict__ h, const float* __restrict__ mask,
    const float* __restrict__ W1, const float* __restrict__ b1,
    const float* __restrict__ W2, const float* __restrict__ b2,
    float* __restrict__ out) {
  __shared__ float part[3][128];
  __shared__ float pl[128];
  __shared__ float hid[128];
  int b = blockIdx.x, t = threadIdx.x, g = t >> 6, cp = (t & 63)*2;
  float a0 = 0.f, a1 = 0.f;
  for (int n = g*128; n < g*128+128; ++n) {
    float mv = mask[(size_t)b*Nn + n];
    bf16x2 v = *(const bf16x2*)(h + ((size_t)b*Nn + n)*128 + cp);
    a0 = fmaf((float)v[0], mv, a0);
    a1 = fmaf((float)v[1], mv, a1);
  }
  if (g > 0) { part[g-1][cp] = a0; part[g-1][cp+1] = a1; }
  __syncthreads();
  if (g == 0) {
    pl[cp]   = a0 + part[0][cp]   + part[1][cp]   + part[2][cp];
    pl[cp+1] = a1 + part[0][cp+1] + part[1][cp+1] + part[2][cp+1];
  }
  __syncthreads();
  if (t < 128) {
    float a = b1[t];
#pragma unroll 4
    for (int j = 0; j < 128; ++j) a = fmaf(pl[j], W1[j*128 + t], a);
    hid[t] = fmaxf(a, 0.f);
  }
  __syncthreads();
  if (t < 128) {
    float a = b2[t];
#pragma unroll 4
    for (int j = 0; j < 128; ++j) a = fmaf(hid[j], W2[j*128 + t], a);
    out[(size_t)b*128 + t] = a;
  }
}

// -------------------------------------------------- launch
extern "C" void kernel_launch(void* const* d_in, const int* in_sizes, int n_in,
                              void* d_out, int out_size, void* d_ws, size_t ws_size,
                              hipStream_t stream) {
  const float* jets = (const float*)d_in[0];
  const float* mask = (const float*)d_in[1];
  const float* eW0  = (const float*)d_in[2];
  const float* eb0  = (const float*)d_in[3];
  const float* eW1  = (const float*)d_in[4];
  const float* eb1  = (const float*)d_in[5];
  const float* Wm   = (const float*)d_in[6];
  const float* bm   = (const float*)d_in[7];
  const float* Wu   = (const float*)d_in[8];
  const float* bu   = (const float*)d_in[9];
  const float* rW1  = (const float*)d_in[10];
  const float* rb1  = (const float*)d_in[11];
  const float* rW2  = (const float*)d_in[12];
  const float* rb2  = (const float*)d_in[13];
  float* out = (float*)d_out;

  bf16* h     = (bf16*)d_ws;                    // ROWS*128
  bf16* msgTA = h     + (size_t)ROWS*128;       // ROWS*128 (layout [b][c][n])
  bf16* msgTB = msgTA + (size_t)ROWS*128;       // ROWS*128 (ping-pong)
  bf16* WTe   = msgTB + (size_t)ROWS*128;       // 128*128
  bf16* WTm   = WTe   + 128*128;                // 3*128*128
  bf16* WTu   = WTm   + 3*128*128;              // 3*256*128
  int*  flags = (int*)(WTu + 3*256*128);        // 2*128 per-batch counters

  hipMemsetAsync(flags, 0, 2*128*sizeof(int), stream);
  prep_all<<<640, 256, 0, stream>>>(eW1, Wm, Wu, WTe, WTm, WTu);
  embed_msg0<<<ROWS/128, 256, 0, stream>>>(jets, eW0, eb0, WTe, eb1,
                                           WTm, bm, h, msgTA);
  mp_persist<<<Bb*4, 256, 0, stream>>>(jets, mask, msgTA, msgTB, h,
                                       WTu, bu, WTm, bm, flags);
  pool_readout<<<Bb, 256, 0, stream>>>(h, mask, rW1, rb1, rW2, rb2, out);
}

// Round 10
// 232.552 us; speedup vs baseline: 1.6829x; 1.6829x over previous
//
#include <hip/hip_runtime.h>
#include <stdint.h>
#include <stddef.h>

#define Bb 128
#define Nn 512
#define Hh 128
#define ROWS (Bb*Nn)

typedef __bf16 bf16;
typedef __bf16 bf16x2 __attribute__((ext_vector_type(2)));
typedef __bf16 bf16x4 __attribute__((ext_vector_type(4)));
typedef __bf16 bf16x8 __attribute__((ext_vector_type(8)));
typedef float  f32x4  __attribute__((ext_vector_type(4)));

__device__ __forceinline__ void glds16(const void* g, void* l) {
  __builtin_amdgcn_global_load_lds(
      (const __attribute__((address_space(1))) void*)g,
      (__attribute__((address_space(3))) void*)l, 16, 0, 0);
}

// -------------------------------------------------- weight prep (all in one)
// fp32 W[k][c] -> bf16 W^T[c][k ^ ((c&7)<<3)]  (swizzle pre-applied)
__global__ __launch_bounds__(256) void prep_all(
    const float* __restrict__ eW1, const float* __restrict__ Wm,
    const float* __restrict__ Wu, bf16* __restrict__ WTe,
    bf16* __restrict__ WTm, bf16* __restrict__ WTu) {
  int idx = blockIdx.x*256 + threadIdx.x;
  if (idx < 16384) {                       // eW1: 128x128
    int k = idx >> 7, c = idx & 127;
    WTe[c*128 + (k ^ ((c & 7) << 3))] = (bf16)eW1[idx];
  } else if (idx < 16384 + 49152) {        // Wm: 3x128x128
    int sub = idx - 16384;
    int m = sub >> 14, r = sub & 16383;
    int k = r >> 7, c = r & 127;
    WTm[m*16384 + c*128 + (k ^ ((c & 7) << 3))] = (bf16)Wm[sub];
  } else if (idx < 16384 + 49152 + 98304) { // Wu: 3x256x128
    int sub = idx - 65536;
    int m = sub >> 15, r = sub & 32767;
    int k = r >> 7, c = r & 127;
    WTu[m*32768 + c*256 + (k ^ ((c & 7) << 3))] = (bf16)Wu[sub];
  }
}

// -------------------------------------------------- fused embed L1+L2+msg0
// h = relu(relu(jets@W0+b0)@W1+b1); msgT0 = relu(h@Wm0+bm0)^T. 128 rows/block.
__global__ __launch_bounds__(256) void embed_msg0(
    const float* __restrict__ jets, const float* __restrict__ W0,
    const float* __restrict__ b0, const bf16* __restrict__ WTe,
    const float* __restrict__ b1, const bf16* __restrict__ WTm0,
    const float* __restrict__ bm0, bf16* __restrict__ h,
    bf16* __restrict__ msgT) {
  __shared__ float sW0[8*128];
  __shared__ float sb0[128];
  __shared__ bf16 h0s[128*128];   // swizzled; reused for h-tile later
  __shared__ bf16 sWT[128*128];   // swizzled W1^T
  const int t = threadIdx.x;
  const int w = t >> 6, lane = t & 63, l15 = lane & 15, g = lane >> 4;
  const int row_blk = blockIdx.x*128;
  for (int q = w; q < 32; q += 4)
    glds16((const char*)WTe + q*1024 + lane*16, (char*)(void*)sWT + q*1024);
  for (int i = t; i < 8*128; i += 256) sW0[i] = W0[i];
  if (t < 128) sb0[t] = b0[t];
  __syncthreads();
  // layer 1: thread owns 1 row, 64 cols
  {
    const int row = t & 127, colbase = (t >> 7) * 64;
    const float4* jp = (const float4*)(jets + ((size_t)row_blk + row)*8);
    float4 x0 = jp[0], x1 = jp[1];
    float x[8] = {x0.x,x0.y,x0.z,x0.w,x1.x,x1.y,x1.z,x1.w};
    const int sw = (row & 7) << 3;
#pragma unroll
    for (int cg = 0; cg < 16; ++cg) {
      int c0 = colbase + cg*4;
      bf16x4 o;
#pragma unroll
      for (int j = 0; j < 4; ++j) {
        float a = sb0[c0+j];
#pragma unroll
        for (int f = 0; f < 8; ++f) a = fmaf(x[f], sW0[f*128 + c0 + j], a);
        o[j] = (bf16)fmaxf(a, 0.f);
      }
      *(bf16x4*)(h0s + row*128 + (c0 ^ sw)) = o;
    }
  }
  __syncthreads();
  // layer 2: MFMA, 4 waves 2x2
  const int wr = (w & 1)*64, wc = (w >> 1)*64;
  f32x4 acc[4][4];
#pragma unroll
  for (int m = 0; m < 4; ++m)
#pragma unroll
    for (int n = 0; n < 4; ++n) acc[m][n] = (f32x4){0.f,0.f,0.f,0.f};
#pragma unroll
  for (int kk = 0; kk < 128; kk += 32) {
    bf16x8 bfr[4], wfr[4];
#pragma unroll
    for (int n = 0; n < 4; ++n) {
      int row = wr + n*16 + l15;
      bfr[n] = *(const bf16x8*)(h0s + row*128 + ((kk + 8*g) ^ ((row & 7) << 3)));
    }
#pragma unroll
    for (int m = 0; m < 4; ++m) {
      int c = wc + m*16 + l15;
      wfr[m] = *(const bf16x8*)(sWT + c*128 + ((kk + 8*g) ^ ((c & 7) << 3)));
    }
#pragma unroll
    for (int m = 0; m < 4; ++m)
#pragma unroll
      for (int n = 0; n < 4; ++n)
        acc[m][n] = __builtin_amdgcn_mfma_f32_16x16x32_bf16(wfr[m], bfr[n], acc[m][n], 0,0,0);
  }
  __syncthreads();   // everyone done reading h0s before overwrite
#pragma unroll
  for (int m = 0; m < 4; ++m) {
    f32x4 bs = *(const f32x4*)(b1 + wc + m*16 + g*4);
#pragma unroll
    for (int n = 0; n < 4; ++n) {
      int lr = wr + n*16 + l15;
      int r = row_blk + lr;
      int c0 = wc + m*16 + g*4;
      bf16x4 o;
#pragma unroll
      for (int j = 0; j < 4; ++j) o[j] = (bf16)fmaxf(acc[m][n][j] + bs[j], 0.f);
      *(bf16x4*)(h + (size_t)r*128 + c0) = o;
      *(bf16x4*)(h0s + lr*128 + (c0 ^ ((lr & 7) << 3))) = o;
    }
  }
  __syncthreads();
  // msg0: msgT = relu(htile @ Wm0 + bm0), TRANSOUT; Wm0 frags from global(L2)
  {
    f32x4 acc2[4][4];
#pragma unroll
    for (int m = 0; m < 4; ++m)
#pragma unroll
      for (int n = 0; n < 4; ++n) acc2[m][n] = (f32x4){0.f,0.f,0.f,0.f};
#pragma unroll
    for (int kk = 0; kk < 128; kk += 32) {
      bf16x8 bfr[4], wfr[4];
#pragma unroll
      for (int n = 0; n < 4; ++n) {
        int lr = wr + n*16 + l15;
        bfr[n] = *(const bf16x8*)(h0s + lr*128 + ((kk + 8*g) ^ ((lr & 7) << 3)));
      }
#pragma unroll
      for (int m = 0; m < 4; ++m) {
        int c = wc + m*16 + l15;
        wfr[m] = *(const bf16x8*)(WTm0 + c*128 + ((kk + 8*g) ^ ((c & 7) << 3)));
      }
#pragma unroll
      for (int m = 0; m < 4; ++m)
#pragma unroll
        for (int n = 0; n < 4; ++n)
          acc2[m][n] = __builtin_amdgcn_mfma_f32_16x16x32_bf16(bfr[n], wfr[m], acc2[m][n], 0,0,0);
    }
    const int b = row_blk >> 9;
    const int rbase = (row_blk & 511) + wr;
#pragma unroll
    for (int m = 0; m < 4; ++m) {
      int c = wc + m*16 + l15;
      float bc = bm0[c];
#pragma unroll
      for (int n = 0; n < 4; ++n) {
        int rl = rbase + n*16 + g*4;
        bf16x4 o;
#pragma unroll
        for (int j = 0; j < 4; ++j) o[j] = (bf16)fmaxf(acc2[m][n][j] + bc, 0.f);
        *(bf16x4*)(msgT + ((size_t)(b*128 + c))*512 + rl) = o;
      }
    }
  }
}

// -------------------------------------------------- fused per-iteration kernel
// Round-7 geometry, LDS repacked to 52KB -> 3 blocks/CU (was 64KB -> 2).
// Layout: [0,18432) Xs | [18432,20480) cbs | [20480,53248) aggs.
// htile [0,32768) overlays dead Xs/cbs AND the aggs head -- safe because the
// barrier between Phase-B K-loop (last aggs reads) and the epilogue (first
// htile writes) drains all aggs readers first.
// Phase A: agg -> LDS. Phase B: h_new = relu([h|agg]@Wu+bu)*mask (in-place h).
// Phase C (DO_MSG): msgTout = relu(h_new@Wm+bm)^T. msgTin != msgTout.
template<bool COMPUTE_L, bool DO_MSG>
__global__ __launch_bounds__(256, 3) void iter_fused(
    const float* __restrict__ jets, const float* __restrict__ mask,
    float* __restrict__ rsum, const bf16* __restrict__ msgTin,
    bf16* __restrict__ h,
    const bf16* __restrict__ WTu, const float* __restrict__ bu,
    const bf16* __restrict__ WTm, const float* __restrict__ bm,
    bf16* __restrict__ msgTout) {
  __shared__ __align__(16) char smem[53248];
  float* Xs    = (float*)smem;                // [512*9]   18KB (phase A)
  float* cbs   = (float*)(smem + 18432);      // [512]      2KB (phase A)
  bf16*  aggs  = (bf16*)(smem + 20480);       // [128][128] 32KB
  bf16*  htile = (bf16*)smem;                 // [128][128] 32KB (phase B/C)
  const int t = threadIdx.x;
  const int b  = blockIdx.x & 127;
  const int ic = blockIdx.x >> 7;             // 0..3
  const int i0 = ic*128;
  const int w = t >> 6, lane = t & 63, l15 = lane & 15, g = lane >> 4;

  // ---- stage Xs / cbs
  const float* jb = jets + (size_t)b*Nn*8;
  for (int j = t; j < Nn; j += 256) {
    float s2 = 0.f;
#pragma unroll
    for (int f = 0; f < 8; ++f) { float v = jb[j*8+f]; Xs[j*9+f] = v; s2 = fmaf(v,v,s2); }
    cbs[j] = s2 + (mask[(size_t)b*Nn+j] > 0.f ? 0.f : 1e9f);
  }
  __syncthreads();

  // ================= Phase A: agg rows i0 + w*32 .. +31
  {
    const int i0w = i0 + w*32;
    float xi2[2][8], sqi[2], r_i[2], lsum[2];
#pragma unroll
    for (int r = 0; r < 2; ++r) {
      int i = i0w + r*16 + l15;
      float sq = 0.f;
#pragma unroll
      for (int f = 0; f < 8; ++f) {
        float v = Xs[i*9+f];
        xi2[r][f] = 2.f*v;
        sq = fmaf(v, v, sq);
      }
      sqi[r] = sq;
      lsum[r] = 0.f;
      if (!COMPUTE_L) r_i[r] = rsum[(size_t)b*Nn+i];
    }
    f32x4 acc[2][8];
#pragma unroll
    for (int r = 0; r < 2; ++r)
#pragma unroll
      for (int m = 0; m < 8; ++m) acc[r][m] = (f32x4){0.f,0.f,0.f,0.f};
    const bf16* mB = msgTin + (size_t)b*128*512;
#pragma unroll 2
    for (int j0 = 0; j0 < Nn; j0 += 32) {
      bf16x8 afr[8];
#pragma unroll
      for (int m = 0; m < 8; ++m)
        afr[m] = *(const bf16x8*)(mB + (size_t)(m*16 + l15)*512 + j0 + 8*g);
      bf16x8 pfr[2];
#pragma unroll
      for (int r = 0; r < 2; ++r)
#pragma unroll
        for (int e = 0; e < 8; ++e) {
          int j = j0 + 8*g + e;
          float d = -(cbs[j] + sqi[r]);
#pragma unroll
          for (int f = 0; f < 8; ++f) d = fmaf(xi2[r][f], Xs[j*9+f], d);
          float ev = __expf(d);
          if (COMPUTE_L) lsum[r] += ev;
          pfr[r][e] = (bf16)ev;
        }
#pragma unroll
      for (int m = 0; m < 8; ++m)
#pragma unroll
        for (int r = 0; r < 2; ++r)
          acc[r][m] = __builtin_amdgcn_mfma_f32_16x16x32_bf16(afr[m], pfr[r], acc[r][m], 0,0,0);
    }
    if (COMPUTE_L) {
#pragma unroll
      for (int r = 0; r < 2; ++r) {
        float s = lsum[r];
        s += __shfl_xor(s, 16, 64);
        s += __shfl_xor(s, 32, 64);
        r_i[r] = 1.f/s;
        if (g == 0) rsum[(size_t)b*Nn + i0w + r*16 + l15] = r_i[r];
      }
    }
    // epilogue -> aggs LDS (swizzled)
#pragma unroll
    for (int r = 0; r < 2; ++r) {
      int lr = w*32 + r*16 + l15;      // local row 0..127
#pragma unroll
      for (int m = 0; m < 8; ++m) {
        bf16x4 o;
#pragma unroll
        for (int j = 0; j < 4; ++j) o[j] = (bf16)(acc[r][m][j] * r_i[r]);
        int c0 = m*16 + g*4;
        *(bf16x4*)(aggs + lr*128 + (c0 ^ ((lr & 7) << 3))) = o;
      }
    }
  }
  __syncthreads();   // aggs visible; Xs dead

  // ================= Phase B: h_new = relu([h|agg] @ Wu + bu) * mask
  const int wr = (w & 1)*64, wc = (w >> 1)*64;
  const size_t growbase = (size_t)b*Nn + i0;
  {
    f32x4 acc[4][4];
#pragma unroll
    for (int m = 0; m < 4; ++m)
#pragma unroll
      for (int n = 0; n < 4; ++n) acc[m][n] = (f32x4){0.f,0.f,0.f,0.f};
#pragma unroll
    for (int kk = 0; kk < 256; kk += 32) {
      bf16x8 bfr[4];
      if (kk < 128) {
#pragma unroll
        for (int n = 0; n < 4; ++n)
          bfr[n] = *(const bf16x8*)(h + (growbase + wr + n*16 + l15)*128 + kk + 8*g);
      } else {
#pragma unroll
        for (int n = 0; n < 4; ++n) {
          int lr = wr + n*16 + l15;
          int kl = (kk - 128) + 8*g;
          bfr[n] = *(const bf16x8*)(aggs + lr*128 + (kl ^ ((lr & 7) << 3)));
        }
      }
      bf16x8 wfr[4];
#pragma unroll
      for (int m = 0; m < 4; ++m) {
        int c = wc + m*16 + l15;
        wfr[m] = *(const bf16x8*)(WTu + c*256 + ((kk + 8*g) ^ ((c & 7) << 3)));
      }
#pragma unroll
      for (int m = 0; m < 4; ++m)
#pragma unroll
        for (int n = 0; n < 4; ++n)
          acc[m][n] = __builtin_amdgcn_mfma_f32_16x16x32_bf16(wfr[m], bfr[n], acc[m][n], 0,0,0);
    }
    __syncthreads();  // all aggs reads + h reads drained (htile overlays aggs head)
#pragma unroll
    for (int m = 0; m < 4; ++m) {
      f32x4 bs = *(const f32x4*)(bu + wc + m*16 + g*4);
#pragma unroll
      for (int n = 0; n < 4; ++n) {
        int lr = wr + n*16 + l15;
        size_t r = growbase + lr;
        float mv = mask[r];
        bf16x4 o;
#pragma unroll
        for (int j = 0; j < 4; ++j)
          o[j] = (bf16)(fmaxf(acc[m][n][j] + bs[j], 0.f) * mv);
        int c0 = wc + m*16 + g*4;
        *(bf16x4*)(h + r*128 + c0) = o;
        if (DO_MSG)
          *(bf16x4*)(htile + lr*128 + (c0 ^ ((lr & 7) << 3))) = o;
      }
    }
  }
  if (!DO_MSG) return;
  __syncthreads();   // htile visible

  // ================= Phase C: msgTout = relu(h_new @ Wm + bm)^T
  {
    f32x4 acc[4][4];
#pragma unroll
    for (int m = 0; m < 4; ++m)
#pragma unroll
      for (int n = 0; n < 4; ++n) acc[m][n] = (f32x4){0.f,0.f,0.f,0.f};
#pragma unroll
    for (int kk = 0; kk < 128; kk += 32) {
      bf16x8 bfr[4], wfr[4];
#pragma unroll
      for (int n = 0; n < 4; ++n) {
        int lr = wr + n*16 + l15;
        bfr[n] = *(const bf16x8*)(htile + lr*128 + ((kk + 8*g) ^ ((lr & 7) << 3)));
      }
#pragma unroll
      for (int m = 0; m < 4; ++m) {
        int c = wc + m*16 + l15;
        wfr[m] = *(const bf16x8*)(WTm + c*128 + ((kk + 8*g) ^ ((c & 7) << 3)));
      }
#pragma unroll
      for (int m = 0; m < 4; ++m)
#pragma unroll
        for (int n = 0; n < 4; ++n)
          acc[m][n] = __builtin_amdgcn_mfma_f32_16x16x32_bf16(bfr[n], wfr[m], acc[m][n], 0,0,0);
    }
#pragma unroll
    for (int m = 0; m < 4; ++m) {
      int c = wc + m*16 + l15;
      float bc = bm[c];
#pragma unroll
      for (int n = 0; n < 4; ++n) {
        int rl = i0 + wr + n*16 + g*4;
        bf16x4 o;
#pragma unroll
        for (int j = 0; j < 4; ++j) o[j] = (bf16)fmaxf(acc[m][n][j] + bc, 0.f);
        *(bf16x4*)(msgTout + ((size_t)(b*128 + c))*512 + rl) = o;
      }
    }
  }
}

// -------------------------------------------------- fused pool + readout
__global__ __launch_bounds__(256) void pool_readout(
    const bf16* __restrict__ h, const float* __restrict__ mask,
    const float* __restrict__ W1, const float* __restrict__ b1,
    const float* __restrict__ W2, const float* __restrict__ b2,
    float* __restrict__ out) {
  __shared__ float part[3][128];
  __shared__ float pl[128];
  __shared__ float hid[128];
  int b = blockIdx.x, t = threadIdx.x, g = t >> 6, cp = (t & 63)*2;
  float a0 = 0.f, a1 = 0.f;
  for (int n = g*128; n < g*128+128; ++n) {
    float mv = mask[(size_t)b*Nn + n];
    bf16x2 v = *(const bf16x2*)(h + ((size_t)b*Nn + n)*128 + cp);
    a0 = fmaf((float)v[0], mv, a0);
    a1 = fmaf((float)v[1], mv, a1);
  }
  if (g > 0) { part[g-1][cp] = a0; part[g-1][cp+1] = a1; }
  __syncthreads();
  if (g == 0) {
    pl[cp]   = a0 + part[0][cp]   + part[1][cp]   + part[2][cp];
    pl[cp+1] = a1 + part[0][cp+1] + part[1][cp+1] + part[2][cp+1];
  }
  __syncthreads();
  if (t < 128) {
    float a = b1[t];
#pragma unroll 4
    for (int j = 0; j < 128; ++j) a = fmaf(pl[j], W1[j*128 + t], a);
    hid[t] = fmaxf(a, 0.f);
  }
  __syncthreads();
  if (t < 128) {
    float a = b2[t];
#pragma unroll 4
    for (int j = 0; j < 128; ++j) a = fmaf(hid[j], W2[j*128 + t], a);
    out[(size_t)b*128 + t] = a;
  }
}

// -------------------------------------------------- launch
extern "C" void kernel_launch(void* const* d_in, const int* in_sizes, int n_in,
                              void* d_out, int out_size, void* d_ws, size_t ws_size,
                              hipStream_t stream) {
  const float* jets = (const float*)d_in[0];
  const float* mask = (const float*)d_in[1];
  const float* eW0  = (const float*)d_in[2];
  const float* eb0  = (const float*)d_in[3];
  const float* eW1  = (const float*)d_in[4];
  const float* eb1  = (const float*)d_in[5];
  const float* Wm   = (const float*)d_in[6];
  const float* bm   = (const float*)d_in[7];
  const float* Wu   = (const float*)d_in[8];
  const float* bu   = (const float*)d_in[9];
  const float* rW1  = (const float*)d_in[10];
  const float* rb1  = (const float*)d_in[11];
  const float* rW2  = (const float*)d_in[12];
  const float* rb2  = (const float*)d_in[13];
  float* out = (float*)d_out;

  bf16* h     = (bf16*)d_ws;                    // ROWS*128
  bf16* msgTA = h     + (size_t)ROWS*128;       // ROWS*128 (layout [b][c][n])
  bf16* msgTB = msgTA + (size_t)ROWS*128;       // ROWS*128 (ping-pong)
  bf16* WTe   = msgTB + (size_t)ROWS*128;       // 128*128
  bf16* WTm   = WTe   + 128*128;                // 3*128*128
  bf16* WTu   = WTm   + 3*128*128;              // 3*256*128
  float* rsum = (float*)(WTu + 3*256*128);      // ROWS (1/l_i)

  prep_all<<<640, 256, 0, stream>>>(eW1, Wm, Wu, WTe, WTm, WTu);
  embed_msg0<<<ROWS/128, 256, 0, stream>>>(jets, eW0, eb0, WTe, eb1,
                                           WTm, bm, h, msgTA);
  // iter 0 (computes 1/l_i on the fly): msgTA -> msgTB
  iter_fused<true,true><<<Bb*4, 256, 0, stream>>>(
      jets, mask, rsum, msgTA, h,
      WTu, bu, WTm + (size_t)1*128*128, bm + 1*128, msgTB);
  // iter 1: msgTB -> msgTA
  iter_fused<false,true><<<Bb*4, 256, 0, stream>>>(
      jets, mask, rsum, msgTB, h,
      WTu + (size_t)1*256*128, bu + 1*128,
      WTm + (size_t)2*128*128, bm + 2*128, msgTA);
  // iter 2 (no next msg): reads msgTA
  iter_fused<false,false><<<Bb*4, 256, 0, stream>>>(
      jets, mask, rsum, msgTA, h,
      WTu + (size_t)2*256*128, bu + 2*128, nullptr, nullptr, nullptr);

  pool_readout<<<Bb, 256, 0, stream>>>(h, mask, rW1, rb1, rW2, rb2, out);
}

// Round 11
// 211.981 us; speedup vs baseline: 1.8462x; 1.0970x over previous
//
#include <hip/hip_runtime.h>
#include <stdint.h>
#include <stddef.h>

#define Bb 128
#define Nn 512
#define Hh 128
#define ROWS (Bb*Nn)

typedef __bf16 bf16;
typedef __bf16 bf16x2 __attribute__((ext_vector_type(2)));
typedef __bf16 bf16x4 __attribute__((ext_vector_type(4)));
typedef __bf16 bf16x8 __attribute__((ext_vector_type(8)));
typedef float  f32x4  __attribute__((ext_vector_type(4)));

__device__ __forceinline__ void glds16(const void* g, void* l) {
  __builtin_amdgcn_global_load_lds(
      (const __attribute__((address_space(1))) void*)g,
      (__attribute__((address_space(3))) void*)l, 16, 0, 0);
}

// -------------------------------------------------- weight prep (all in one)
// fp32 W[k][c] -> bf16 W^T[c][k ^ ((c&7)<<3)]  (swizzle pre-applied)
__global__ __launch_bounds__(256) void prep_all(
    const float* __restrict__ eW1, const float* __restrict__ Wm,
    const float* __restrict__ Wu, bf16* __restrict__ WTe,
    bf16* __restrict__ WTm, bf16* __restrict__ WTu) {
  int idx = blockIdx.x*256 + threadIdx.x;
  if (idx < 16384) {                       // eW1: 128x128
    int k = idx >> 7, c = idx & 127;
    WTe[c*128 + (k ^ ((c & 7) << 3))] = (bf16)eW1[idx];
  } else if (idx < 16384 + 49152) {        // Wm: 3x128x128
    int sub = idx - 16384;
    int m = sub >> 14, r = sub & 16383;
    int k = r >> 7, c = r & 127;
    WTm[m*16384 + c*128 + (k ^ ((c & 7) << 3))] = (bf16)Wm[sub];
  } else if (idx < 16384 + 49152 + 98304) { // Wu: 3x256x128
    int sub = idx - 65536;
    int m = sub >> 15, r = sub & 32767;
    int k = r >> 7, c = r & 127;
    WTu[m*32768 + c*256 + (k ^ ((c & 7) << 3))] = (bf16)Wu[sub];
  }
}

// -------------------------------------------------- fused embed L1+L2+msg0
// h = relu(relu(jets@W0+b0)@W1+b1); msgT0 = relu(h@Wm0+bm0)^T. 128 rows/block.
__global__ __launch_bounds__(256) void embed_msg0(
    const float* __restrict__ jets, const float* __restrict__ W0,
    const float* __restrict__ b0, const bf16* __restrict__ WTe,
    const float* __restrict__ b1, const bf16* __restrict__ WTm0,
    const float* __restrict__ bm0, bf16* __restrict__ h,
    bf16* __restrict__ msgT) {
  __shared__ float sW0[8*128];
  __shared__ float sb0[128];
  __shared__ bf16 h0s[128*128];   // swizzled; reused for h-tile later
  __shared__ bf16 sWT[128*128];   // swizzled W1^T
  const int t = threadIdx.x;
  const int w = t >> 6, lane = t & 63, l15 = lane & 15, g = lane >> 4;
  const int row_blk = blockIdx.x*128;
  for (int q = w; q < 32; q += 4)
    glds16((const char*)WTe + q*1024 + lane*16, (char*)(void*)sWT + q*1024);
  for (int i = t; i < 8*128; i += 256) sW0[i] = W0[i];
  if (t < 128) sb0[t] = b0[t];
  __syncthreads();
  // layer 1: thread owns 1 row, 64 cols
  {
    const int row = t & 127, colbase = (t >> 7) * 64;
    const float4* jp = (const float4*)(jets + ((size_t)row_blk + row)*8);
    float4 x0 = jp[0], x1 = jp[1];
    float x[8] = {x0.x,x0.y,x0.z,x0.w,x1.x,x1.y,x1.z,x1.w};
    const int sw = (row & 7) << 3;
#pragma unroll
    for (int cg = 0; cg < 16; ++cg) {
      int c0 = colbase + cg*4;
      bf16x4 o;
#pragma unroll
      for (int j = 0; j < 4; ++j) {
        float a = sb0[c0+j];
#pragma unroll
        for (int f = 0; f < 8; ++f) a = fmaf(x[f], sW0[f*128 + c0 + j], a);
        o[j] = (bf16)fmaxf(a, 0.f);
      }
      *(bf16x4*)(h0s + row*128 + (c0 ^ sw)) = o;
    }
  }
  __syncthreads();
  // layer 2: MFMA, 4 waves 2x2
  const int wr = (w & 1)*64, wc = (w >> 1)*64;
  f32x4 acc[4][4];
#pragma unroll
  for (int m = 0; m < 4; ++m)
#pragma unroll
    for (int n = 0; n < 4; ++n) acc[m][n] = (f32x4){0.f,0.f,0.f,0.f};
#pragma unroll
  for (int kk = 0; kk < 128; kk += 32) {
    bf16x8 bfr[4], wfr[4];
#pragma unroll
    for (int n = 0; n < 4; ++n) {
      int row = wr + n*16 + l15;
      bfr[n] = *(const bf16x8*)(h0s + row*128 + ((kk + 8*g) ^ ((row & 7) << 3)));
    }
#pragma unroll
    for (int m = 0; m < 4; ++m) {
      int c = wc + m*16 + l15;
      wfr[m] = *(const bf16x8*)(sWT + c*128 + ((kk + 8*g) ^ ((c & 7) << 3)));
    }
#pragma unroll
    for (int m = 0; m < 4; ++m)
#pragma unroll
      for (int n = 0; n < 4; ++n)
        acc[m][n] = __builtin_amdgcn_mfma_f32_16x16x32_bf16(wfr[m], bfr[n], acc[m][n], 0,0,0);
  }
  __syncthreads();   // everyone done reading h0s before overwrite
#pragma unroll
  for (int m = 0; m < 4; ++m) {
    f32x4 bs = *(const f32x4*)(b1 + wc + m*16 + g*4);
#pragma unroll
    for (int n = 0; n < 4; ++n) {
      int lr = wr + n*16 + l15;
      int r = row_blk + lr;
      int c0 = wc + m*16 + g*4;
      bf16x4 o;
#pragma unroll
      for (int j = 0; j < 4; ++j) o[j] = (bf16)fmaxf(acc[m][n][j] + bs[j], 0.f);
      *(bf16x4*)(h + (size_t)r*128 + c0) = o;
      *(bf16x4*)(h0s + lr*128 + (c0 ^ ((lr & 7) << 3))) = o;
    }
  }
  __syncthreads();
  // msg0: msgT = relu(htile @ Wm0 + bm0), TRANSOUT; Wm0 frags from global(L2)
  {
    f32x4 acc2[4][4];
#pragma unroll
    for (int m = 0; m < 4; ++m)
#pragma unroll
      for (int n = 0; n < 4; ++n) acc2[m][n] = (f32x4){0.f,0.f,0.f,0.f};
#pragma unroll
    for (int kk = 0; kk < 128; kk += 32) {
      bf16x8 bfr[4], wfr[4];
#pragma unroll
      for (int n = 0; n < 4; ++n) {
        int lr = wr + n*16 + l15;
        bfr[n] = *(const bf16x8*)(h0s + lr*128 + ((kk + 8*g) ^ ((lr & 7) << 3)));
      }
#pragma unroll
      for (int m = 0; m < 4; ++m) {
        int c = wc + m*16 + l15;
        wfr[m] = *(const bf16x8*)(WTm0 + c*128 + ((kk + 8*g) ^ ((c & 7) << 3)));
      }
#pragma unroll
      for (int m = 0; m < 4; ++m)
#pragma unroll
        for (int n = 0; n < 4; ++n)
          acc2[m][n] = __builtin_amdgcn_mfma_f32_16x16x32_bf16(bfr[n], wfr[m], acc2[m][n], 0,0,0);
    }
    const int b = row_blk >> 9;
    const int rbase = (row_blk & 511) + wr;
#pragma unroll
    for (int m = 0; m < 4; ++m) {
      int c = wc + m*16 + l15;
      float bc = bm0[c];
#pragma unroll
      for (int n = 0; n < 4; ++n) {
        int rl = rbase + n*16 + g*4;
        bf16x4 o;
#pragma unroll
        for (int j = 0; j < 4; ++j) o[j] = (bf16)fmaxf(acc2[m][n][j] + bc, 0.f);
        *(bf16x4*)(msgT + ((size_t)(b*128 + c))*512 + rl) = o;
      }
    }
  }
}

// -------------------------------------------------- fused per-iteration kernel
// R7 geometry (64KB LDS, 2 blocks/CU, 128-row blocks, wave=32 A-rows / 64x64
// B/C tile) + explicit software pipelining: double-buffered afr (Phase A) and
// bfr/wfr (Phase B/C) global streams. VGPR headroom is free at 2 blocks/CU.
template<bool COMPUTE_L, bool DO_MSG>
__global__ __launch_bounds__(256) void iter_fused(
    const float* __restrict__ jets, const float* __restrict__ mask,
    float* __restrict__ rsum, const bf16* __restrict__ msgTin,
    bf16* __restrict__ h,
    const bf16* __restrict__ WTu, const float* __restrict__ bu,
    const bf16* __restrict__ WTm, const float* __restrict__ bm,
    bf16* __restrict__ msgTout) {
  __shared__ __align__(16) char smem[65536];
  float* Xs    = (float*)smem;                // [512*9]   18KB (phase A)
  float* cbs   = (float*)(smem + 18432);      // [512]      2KB (phase A)
  bf16*  htile = (bf16*)smem;                 // [128][128] 32KB (phase B/C)
  bf16*  aggs  = (bf16*)(smem + 32768);       // [128][128] 32KB
  const int t = threadIdx.x;
  const int b  = blockIdx.x & 127;
  const int ic = blockIdx.x >> 7;             // 0..3
  const int i0 = ic*128;
  const int w = t >> 6, lane = t & 63, l15 = lane & 15, g = lane >> 4;

  // ---- stage Xs / cbs
  const float* jb = jets + (size_t)b*Nn*8;
  for (int j = t; j < Nn; j += 256) {
    float s2 = 0.f;
#pragma unroll
    for (int f = 0; f < 8; ++f) { float v = jb[j*8+f]; Xs[j*9+f] = v; s2 = fmaf(v,v,s2); }
    cbs[j] = s2 + (mask[(size_t)b*Nn+j] > 0.f ? 0.f : 1e9f);
  }
  __syncthreads();

  // ================= Phase A: agg rows i0 + w*32 .. +31 (pipelined)
  {
    const int i0w = i0 + w*32;
    float xi2[2][8], sqi[2], r_i[2], lsum[2];
#pragma unroll
    for (int r = 0; r < 2; ++r) {
      int i = i0w + r*16 + l15;
      float sq = 0.f;
#pragma unroll
      for (int f = 0; f < 8; ++f) {
        float v = Xs[i*9+f];
        xi2[r][f] = 2.f*v;
        sq = fmaf(v, v, sq);
      }
      sqi[r] = sq;
      lsum[r] = 0.f;
      if (!COMPUTE_L) r_i[r] = rsum[(size_t)b*Nn+i];
    }
    f32x4 acc[2][8];
#pragma unroll
    for (int r = 0; r < 2; ++r)
#pragma unroll
      for (int m = 0; m < 8; ++m) acc[r][m] = (f32x4){0.f,0.f,0.f,0.f};

    const bf16* mB = msgTin + (size_t)b*128*512 + (size_t)l15*512 + 8*g;
    bf16x8 afrA[8], afrB[8];
    auto loadA = [&](int J) {
#pragma unroll
      for (int m = 0; m < 8; ++m) afrA[m] = *(const bf16x8*)(mB + m*8192 + J);
    };
    auto loadB = [&](int J) {
#pragma unroll
      for (int m = 0; m < 8; ++m) afrB[m] = *(const bf16x8*)(mB + m*8192 + J);
    };
    auto computeA = [&](const bf16x8* afr, int j0) {
      bf16x8 pfr[2];
#pragma unroll
      for (int e = 0; e < 8; ++e) {
        int j = j0 + 8*g + e;
        float xj[8];
#pragma unroll
        for (int f = 0; f < 8; ++f) xj[f] = Xs[j*9+f];
        float cb = cbs[j];
        float d0 = -(cb + sqi[0]);
        float d1 = -(cb + sqi[1]);
#pragma unroll
        for (int f = 0; f < 8; ++f) {
          d0 = fmaf(xi2[0][f], xj[f], d0);
          d1 = fmaf(xi2[1][f], xj[f], d1);
        }
        float ev0 = __expf(d0), ev1 = __expf(d1);
        if (COMPUTE_L) { lsum[0] += ev0; lsum[1] += ev1; }
        pfr[0][e] = (bf16)ev0;
        pfr[1][e] = (bf16)ev1;
      }
#pragma unroll
      for (int m = 0; m < 8; ++m) {
        acc[0][m] = __builtin_amdgcn_mfma_f32_16x16x32_bf16(afr[m], pfr[0], acc[0][m], 0,0,0);
        acc[1][m] = __builtin_amdgcn_mfma_f32_16x16x32_bf16(afr[m], pfr[1], acc[1][m], 0,0,0);
      }
    };

    loadA(0);
#pragma unroll
    for (int jj = 0; jj < Nn; jj += 64) {
      loadB(jj + 32);
      computeA(afrA, jj);
      if (jj + 64 < Nn) loadA(jj + 64);
      computeA(afrB, jj + 32);
    }

    if (COMPUTE_L) {
#pragma unroll
      for (int r = 0; r < 2; ++r) {
        float s = lsum[r];
        s += __shfl_xor(s, 16, 64);
        s += __shfl_xor(s, 32, 64);
        r_i[r] = 1.f/s;
        if (g == 0) rsum[(size_t)b*Nn + i0w + r*16 + l15] = r_i[r];
      }
    }
    // epilogue -> aggs LDS (swizzled)
#pragma unroll
    for (int r = 0; r < 2; ++r) {
      int lr = w*32 + r*16 + l15;      // local row 0..127
#pragma unroll
      for (int m = 0; m < 8; ++m) {
        bf16x4 o;
#pragma unroll
        for (int j = 0; j < 4; ++j) o[j] = (bf16)(acc[r][m][j] * r_i[r]);
        int c0 = m*16 + g*4;
        *(bf16x4*)(aggs + lr*128 + (c0 ^ ((lr & 7) << 3))) = o;
      }
    }
  }
  __syncthreads();   // aggs visible; Xs dead

  // ================= Phase B: h_new = relu([h|agg] @ Wu + bu) * mask (pipelined)
  const int wr = (w & 1)*64, wc = (w >> 1)*64;
  const size_t growbase = (size_t)b*Nn + i0;
  {
    const bf16* hp[4];
    const bf16* agp[4];
    int swr[4];
#pragma unroll
    for (int n = 0; n < 4; ++n) {
      int lr = wr + n*16 + l15;
      hp[n]  = h + (growbase + lr)*128 + 8*g;
      agp[n] = aggs + lr*128;
      swr[n] = (lr & 7) << 3;
    }
    const bf16* wup[4];
    int swc[4];
#pragma unroll
    for (int m = 0; m < 4; ++m) {
      int c = wc + m*16 + l15;
      wup[m] = WTu + c*256;
      swc[m] = (c & 7) << 3;
    }
    f32x4 acc[4][4];
#pragma unroll
    for (int m = 0; m < 4; ++m)
#pragma unroll
      for (int n = 0; n < 4; ++n) acc[m][n] = (f32x4){0.f,0.f,0.f,0.f};

    bf16x8 bfrA[4], bfrB[4], wfrA[4], wfrB[4];
    auto loadSA = [&](int kk) {
#pragma unroll
      for (int n = 0; n < 4; ++n) {
        if (kk < 128) bfrA[n] = *(const bf16x8*)(hp[n] + kk);
        else          bfrA[n] = *(const bf16x8*)(agp[n] + (((kk - 128) + 8*g) ^ swr[n]));
      }
#pragma unroll
      for (int m = 0; m < 4; ++m)
        wfrA[m] = *(const bf16x8*)(wup[m] + ((kk + 8*g) ^ swc[m]));
    };
    auto loadSB = [&](int kk) {
#pragma unroll
      for (int n = 0; n < 4; ++n) {
        if (kk < 128) bfrB[n] = *(const bf16x8*)(hp[n] + kk);
        else          bfrB[n] = *(const bf16x8*)(agp[n] + (((kk - 128) + 8*g) ^ swr[n]));
      }
#pragma unroll
      for (int m = 0; m < 4; ++m)
        wfrB[m] = *(const bf16x8*)(wup[m] + ((kk + 8*g) ^ swc[m]));
    };
    auto mfmaS = [&](const bf16x8* bfr, const bf16x8* wfr) {
#pragma unroll
      for (int m = 0; m < 4; ++m)
#pragma unroll
        for (int n = 0; n < 4; ++n)
          acc[m][n] = __builtin_amdgcn_mfma_f32_16x16x32_bf16(wfr[m], bfr[n], acc[m][n], 0,0,0);
    };

    loadSA(0);
#pragma unroll
    for (int kk = 0; kk < 256; kk += 64) {
      loadSB(kk + 32);
      mfmaS(bfrA, wfrA);
      if (kk + 64 < 256) loadSA(kk + 64);
      mfmaS(bfrB, wfrB);
    }

    __syncthreads();  // all aggs reads + h reads drained before in-place write
#pragma unroll
    for (int m = 0; m < 4; ++m) {
      f32x4 bs = *(const f32x4*)(bu + wc + m*16 + g*4);
#pragma unroll
      for (int n = 0; n < 4; ++n) {
        int lr = wr + n*16 + l15;
        size_t r = growbase + lr;
        float mv = mask[r];
        bf16x4 o;
#pragma unroll
        for (int j = 0; j < 4; ++j)
          o[j] = (bf16)(fmaxf(acc[m][n][j] + bs[j], 0.f) * mv);
        int c0 = wc + m*16 + g*4;
        *(bf16x4*)(h + r*128 + c0) = o;
        if (DO_MSG)
          *(bf16x4*)(htile + lr*128 + (c0 ^ ((lr & 7) << 3))) = o;
      }
    }
  }
  if (!DO_MSG) return;
  __syncthreads();   // htile visible

  // ================= Phase C: msgTout = relu(h_new @ Wm + bm)^T (wfr pipelined)
  {
    const bf16* htp[4];
    int swr[4];
#pragma unroll
    for (int n = 0; n < 4; ++n) {
      int lr = wr + n*16 + l15;
      htp[n] = htile + lr*128;
      swr[n] = (lr & 7) << 3;
    }
    const bf16* wmp[4];
    int swc[4];
#pragma unroll
    for (int m = 0; m < 4; ++m) {
      int c = wc + m*16 + l15;
      wmp[m] = WTm + c*128;
      swc[m] = (c & 7) << 3;
    }
    f32x4 acc[4][4];
#pragma unroll
    for (int m = 0; m < 4; ++m)
#pragma unroll
      for (int n = 0; n < 4; ++n) acc[m][n] = (f32x4){0.f,0.f,0.f,0.f};

    bf16x8 wfrA[4], wfrB[4];
    auto loadWA = [&](int kk) {
#pragma unroll
      for (int m = 0; m < 4; ++m)
        wfrA[m] = *(const bf16x8*)(wmp[m] + ((kk + 8*g) ^ swc[m]));
    };
    auto loadWB = [&](int kk) {
#pragma unroll
      for (int m = 0; m < 4; ++m)
        wfrB[m] = *(const bf16x8*)(wmp[m] + ((kk + 8*g) ^ swc[m]));
    };
    auto stepC = [&](const bf16x8* wfr, int kk) {
      bf16x8 bfr[4];
#pragma unroll
      for (int n = 0; n < 4; ++n)
        bfr[n] = *(const bf16x8*)(htp[n] + (((kk + 8*g)) ^ swr[n]));
#pragma unroll
      for (int m = 0; m < 4; ++m)
#pragma unroll
        for (int n = 0; n < 4; ++n)
          acc[m][n] = __builtin_amdgcn_mfma_f32_16x16x32_bf16(bfr[n], wfr[m], acc[m][n], 0,0,0);
    };

    loadWA(0);
#pragma unroll
    for (int kk = 0; kk < 128; kk += 64) {
      loadWB(kk + 32);
      stepC(wfrA, kk);
      if (kk + 64 < 128) loadWA(kk + 64);
      stepC(wfrB, kk + 32);
    }

#pragma unroll
    for (int m = 0; m < 4; ++m) {
      int c = wc + m*16 + l15;
      float bc = bm[c];
#pragma unroll
      for (int n = 0; n < 4; ++n) {
        int rl = i0 + wr + n*16 + g*4;
        bf16x4 o;
#pragma unroll
        for (int j = 0; j < 4; ++j) o[j] = (bf16)fmaxf(acc[m][n][j] + bc, 0.f);
        *(bf16x4*)(msgTout + ((size_t)(b*128 + c))*512 + rl) = o;
      }
    }
  }
}

// -------------------------------------------------- fused pool + readout
__global__ __launch_bounds__(256) void pool_readout(
    const bf16* __restrict__ h, const float* __restrict__ mask,
    const float* __restrict__ W1, const float* __restrict__ b1,
    const float* __restrict__ W2, const float* __restrict__ b2,
    float* __restrict__ out) {
  __shared__ float part[3][128];
  __shared__ float pl[128];
  __shared__ float hid[128];
  int b = blockIdx.x, t = threadIdx.x, g = t >> 6, cp = (t & 63)*2;
  float a0 = 0.f, a1 = 0.f;
  for (int n = g*128; n < g*128+128; ++n) {
    float mv = mask[(size_t)b*Nn + n];
    bf16x2 v = *(const bf16x2*)(h + ((size_t)b*Nn + n)*128 + cp);
    a0 = fmaf((float)v[0], mv, a0);
    a1 = fmaf((float)v[1], mv, a1);
  }
  if (g > 0) { part[g-1][cp] = a0; part[g-1][cp+1] = a1; }
  __syncthreads();
  if (g == 0) {
    pl[cp]   = a0 + part[0][cp]   + part[1][cp]   + part[2][cp];
    pl[cp+1] = a1 + part[0][cp+1] + part[1][cp+1] + part[2][cp+1];
  }
  __syncthreads();
  if (t < 128) {
    float a = b1[t];
#pragma unroll 4
    for (int j = 0; j < 128; ++j) a = fmaf(pl[j], W1[j*128 + t], a);
    hid[t] = fmaxf(a, 0.f);
  }
  __syncthreads();
  if (t < 128) {
    float a = b2[t];
#pragma unroll 4
    for (int j = 0; j < 128; ++j) a = fmaf(hid[j], W2[j*128 + t], a);
    out[(size_t)b*128 + t] = a;
  }
}

// -------------------------------------------------- launch
extern "C" void kernel_launch(void* const* d_in, const int* in_sizes, int n_in,
                              void* d_out, int out_size, void* d_ws, size_t ws_size,
                              hipStream_t stream) {
  const float* jets = (const float*)d_in[0];
  const float* mask = (const float*)d_in[1];
  const float* eW0  = (const float*)d_in[2];
  const float* eb0  = (const float*)d_in[3];
  const float* eW1  = (const float*)d_in[4];
  const float* eb1  = (const float*)d_in[5];
  const float* Wm   = (const float*)d_in[6];
  const float* bm   = (const float*)d_in[7];
  const float* Wu   = (const float*)d_in[8];
  const float* bu   = (const float*)d_in[9];
  const float* rW1  = (const float*)d_in[10];
  const float* rb1  = (const float*)d_in[11];
  const float* rW2  = (const float*)d_in[12];
  const float* rb2  = (const float*)d_in[13];
  float* out = (float*)d_out;

  bf16* h     = (bf16*)d_ws;                    // ROWS*128
  bf16* msgTA = h     + (size_t)ROWS*128;       // ROWS*128 (layout [b][c][n])
  bf16* msgTB = msgTA + (size_t)ROWS*128;       // ROWS*128 (ping-pong)
  bf16* WTe   = msgTB + (size_t)ROWS*128;       // 128*128
  bf16* WTm   = WTe   + 128*128;                // 3*128*128
  bf16* WTu   = WTm   + 3*128*128;              // 3*256*128
  float* rsum = (float*)(WTu + 3*256*128);      // ROWS (1/l_i)

  prep_all<<<640, 256, 0, stream>>>(eW1, Wm, Wu, WTe, WTm, WTu);
  embed_msg0<<<ROWS/128, 256, 0, stream>>>(jets, eW0, eb0, WTe, eb1,
                                           WTm, bm, h, msgTA);
  // iter 0 (computes 1/l_i on the fly): msgTA -> msgTB
  iter_fused<true,true><<<Bb*4, 256, 0, stream>>>(
      jets, mask, rsum, msgTA, h,
      WTu, bu, WTm + (size_t)1*128*128, bm + 1*128, msgTB);
  // iter 1: msgTB -> msgTA
  iter_fused<false,true><<<Bb*4, 256, 0, stream>>>(
      jets, mask, rsum, msgTB, h,
      WTu + (size_t)1*256*128, bu + 1*128,
      WTm + (size_t)2*128*128, bm + 2*128, msgTA);
  // iter 2 (no next msg): reads msgTA
  iter_fused<false,false><<<Bb*4, 256, 0, stream>>>(
      jets, mask, rsum, msgTA, h,
      WTu + (size_t)2*256*128, bu + 2*128, nullptr, nullptr, nullptr);

  pool_readout<<<Bb, 256, 0, stream>>>(h, mask, rW1, rb1, rW2, rb2, out);
}